// Round 4
// baseline (712.841 us; speedup 1.0000x reference)
//
#include <hip/hip_runtime.h>
#include <math.h>

// MoE router: logits = x[16384,2048] @ W^T[2048,64]; softmax; top-2; renorm.
// Compute-bound on the fp32 vector ALU (no fp32 MFMA): 4.3 GFLOP/157TF = 27.4us.
//
// R3 post-mortem: __launch_bounds__(512,2) capped the allocator at 128 VGPRs
// with ~130 live values -> accumulator spills, ~2GB scratch traffic
// (WRITE_SIZE 1.34GB), VALUBusy 6.8%. R4: identical structure, (512,1) ->
// 256-VGPR envelope. Grid is 256 blocks = 1 block/CU = 2 waves/SIMD either
// way, so the wider budget costs zero occupancy.
//
// Delivery model per kk4-step/wave: 4 per-lane x ds_read_b128 (~12cyc) +
// 16 wave-uniform W ds_read_b128 (broadcast, conflict-free) vs 512 VALU-cyc
// -> compute-bound if broadcast b128 ~4cyc (this run probes that).
// LDS: stride-20 rows make both b128 reads and staging writes spread starts
// 4 banks apart -> conflict-free phases; x 40KB + W 5KB = 45KB.

#define NTOK   16384
#define DDIM   2048
#define NE     64
#define TT     512     // tokens per block
#define KS     8       // K splits (grid dim)
#define KRANGE 256     // 2048/8
#define KTILE  16
#define NTILE  16      // KRANGE/KTILE
#define XSTR   20      // LDS row stride in dwords (16 k + 4 pad, 16B-aligned)

__global__ __launch_bounds__(512, 1) void router_gemm(
    const float* __restrict__ x, const float* __restrict__ W,
    float* __restrict__ pws)
{
    __shared__ __align__(16) float xs[TT * XSTR];   // 40 KB
    __shared__ __align__(16) float wsm[NE * XSTR];  //  5 KB

    const int tid  = threadIdx.x;
    const int lane = tid & 63;
    const int wv   = __builtin_amdgcn_readfirstlane(tid >> 6);
    const int eg   = wv & 3;    // expert group: e in [16*eg, 16*eg+16)
    const int th   = wv >> 2;   // token half: 256 tokens
    const int bx   = blockIdx.x;
    const int ks   = bx & 7;    // K-split; same-ks blocks share the W slice
    const int tt   = bx >> 3;   // token tile
    const int tok0 = tt * TT;
    const int kb   = ks * KRANGE;

    // ---- staging maps (x: 2048 float4/tile, 4/thread; W: 256 float4) ----
    const float* xg[4]; int xl[4];
#pragma unroll
    for (int i = 0; i < 4; ++i) {
        const int f = tid + 512 * i;          // 0..2047
        const int r = f >> 2, c4 = f & 3;     // 4 threads/row -> 64B chunks
        xg[i] = x + (size_t)(tok0 + r) * DDIM + kb + 4 * c4;
        xl[i] = r * XSTR + 4 * c4;
    }
    const float* wg = nullptr; int wl = 0;
    if (tid < 256) {
        const int e = tid >> 2, c4 = tid & 3;
        wg = W + (size_t)e * DDIM + kb + 4 * c4;
        wl = e * XSTR + 4 * c4;
    }

    // ---- prologue: stage tile 0 ----
    float4 px[4], pw;
#pragma unroll
    for (int i = 0; i < 4; ++i) px[i] = *(const float4*)xg[i];
    if (tid < 256) pw = *(const float4*)wg;
#pragma unroll
    for (int i = 0; i < 4; ++i) *(float4*)&xs[xl[i]] = px[i];
    if (tid < 256) *(float4*)&wsm[wl] = pw;
    __syncthreads();

    float acc[16][4];   // [expert][token-slot] = 64 VGPR
#pragma unroll
    for (int j = 0; j < 16; ++j)
#pragma unroll
        for (int c = 0; c < 4; ++c) acc[j][c] = 0.f;

    const int xoff = (th * 256 + lane) * XSTR;
    const int woff = eg * 16 * XSTR;

#pragma unroll 1
    for (int t = 0; t < NTILE; ++t) {
        // prefetch tile t+1 into regs; latency hides under 1024 FMAs
        if (t + 1 < NTILE) {
            const int ko = (t + 1) * KTILE;
#pragma unroll
            for (int i = 0; i < 4; ++i) px[i] = *(const float4*)(xg[i] + ko);
            if (tid < 256) pw = *(const float4*)(wg + ko);
        }
#pragma unroll
        for (int kk = 0; kk < KTILE; kk += 4) {
            float4 xf[4];
#pragma unroll
            for (int c = 0; c < 4; ++c)
                xf[c] = *(const float4*)&xs[xoff + c * 64 * XSTR + kk];
#pragma unroll
            for (int j = 0; j < 16; ++j) {
                const float4 w4 = *(const float4*)&wsm[woff + j * XSTR + kk];
#pragma unroll
                for (int c = 0; c < 4; ++c) {
                    acc[j][c] = fmaf(xf[c].x, w4.x, acc[j][c]);
                    acc[j][c] = fmaf(xf[c].y, w4.y, acc[j][c]);
                    acc[j][c] = fmaf(xf[c].z, w4.z, acc[j][c]);
                    acc[j][c] = fmaf(xf[c].w, w4.w, acc[j][c]);
                }
            }
        }
        __syncthreads();          // everyone done reading tile t
        if (t + 1 < NTILE) {
#pragma unroll
            for (int i = 0; i < 4; ++i) *(float4*)&xs[xl[i]] = px[i];
            if (tid < 256) *(float4*)&wsm[wl] = pw;
        }
        __syncthreads();          // tile t+1 visible
    }

    // ---- write partial logits: pws[ks][token][e] ----
#pragma unroll
    for (int c = 0; c < 4; ++c) {
        const int tok = tok0 + th * 256 + c * 64 + lane;
        float* p = pws + ((size_t)ks * NTOK + tok) * NE + eg * 16;
#pragma unroll
        for (int g = 0; g < 4; ++g) {
            float4 o;
            o.x = acc[4 * g + 0][c];
            o.y = acc[4 * g + 1][c];
            o.z = acc[4 * g + 2][c];
            o.w = acc[4 * g + 3][c];
            *(float4*)(p + 4 * g) = o;
        }
    }
}

// reduce 8 K-split partials, softmax, top-2, renorm, write all outputs
__global__ __launch_bounds__(64) void router_fix(
    const float* __restrict__ pws, float* __restrict__ out)
{
    const int t = blockIdx.x * 64 + threadIdx.x;   // token
    float p[NE];
#pragma unroll
    for (int e = 0; e < NE; ++e) p[e] = 0.f;
    // 2 K-splits per iter -> 32 independent b128 loads in flight for latency
#pragma unroll 1
    for (int ks = 0; ks < KS; ks += 2) {
        const float4* q0 = (const float4*)(pws + ((size_t)ks * NTOK + t) * NE);
        const float4* q1 = (const float4*)(pws + ((size_t)(ks + 1) * NTOK + t) * NE);
#pragma unroll
        for (int j = 0; j < 16; ++j) {
            const float4 v0 = q0[j];
            const float4 v1 = q1[j];
            p[4 * j + 0] += v0.x + v1.x;
            p[4 * j + 1] += v0.y + v1.y;
            p[4 * j + 2] += v0.z + v1.z;
            p[4 * j + 3] += v0.w + v1.w;
        }
    }

    float m = p[0];
#pragma unroll
    for (int e = 1; e < NE; ++e) m = fmaxf(m, p[e]);
    float s = 0.f;
#pragma unroll
    for (int e = 0; e < NE; ++e) { p[e] = expf(p[e] - m); s += p[e]; }
    const float inv = 1.f / s;

    // top-2 on exp-values (same order as probs); lax.top_k tie-break =
    // lowest index first -> strict '>' ascending scan
    float v1 = -1.f; int i1 = 0;
#pragma unroll
    for (int e = 0; e < NE; ++e) { if (p[e] > v1) { v1 = p[e]; i1 = e; } }
    float v2 = -1.f; int i2 = 0;
#pragma unroll
    for (int e = 0; e < NE; ++e) { if (e != i1 && p[e] > v2) { v2 = p[e]; i2 = e; } }

    const float ts = v1 + v2;
    float* out_tp = out;              // top_k_probs  [NTOK][2]
    float* out_ti = out + 2 * NTOK;   // top_k_indices[NTOK][2] (float values)
    float* out_p  = out + 4 * NTOK;   // probs        [NTOK][NE]

    out_tp[t * 2 + 0] = v1 / ts;
    out_tp[t * 2 + 1] = v2 / ts;
    out_ti[t * 2 + 0] = (float)i1;
    out_ti[t * 2 + 1] = (float)i2;

    float* po = out_p + (size_t)t * NE;
#pragma unroll
    for (int j = 0; j < 16; ++j) {
        float4 v = make_float4(p[4 * j + 0] * inv, p[4 * j + 1] * inv,
                               p[4 * j + 2] * inv, p[4 * j + 3] * inv);
        *(float4*)(po + 4 * j) = v;
    }
}

extern "C" void kernel_launch(void* const* d_in, const int* in_sizes, int n_in,
                              void* d_out, int out_size, void* d_ws, size_t ws_size,
                              hipStream_t stream) {
    const float* x = (const float*)d_in[0];
    const float* W = (const float*)d_in[1];
    float* out     = (float*)d_out;
    float* pws     = (float*)d_ws;    // needs KS*NTOK*NE*4 = 32 MB scratch

    router_gemm<<<dim3((NTOK / TT) * KS), dim3(512), 0, stream>>>(x, W, pws);
    router_fix<<<dim3(NTOK / 64), dim3(64), 0, stream>>>(pws, out);
}

// Round 5
// 219.350 us; speedup vs baseline: 3.2498x; 3.2498x over previous
//
#include <hip/hip_runtime.h>
#include <math.h>

// MoE router: logits = x[16384,2048] @ W^T[2048,64]; softmax; top-2; renorm.
//
// R5: fp16 split-precision MFMA. x = xh + xl, W = wh + wl (fp16 pairs);
// logits = xh*wh + xl*wh + xh*wl (3 passes, fp32 acc) -> ~2.4e-7 logit RMS
// error, below fp32 reassociation noise (R1-R4 passed with ~1e-6).
// Compute: 3 x 4.3GF @ 2.5PF = 1.6us. Memory: x 134MB once = 21us -> HBM-bound.
//
// No LDS / no barriers in the K-loop: A and B frags load straight
// global->VGPR. MFMA 16x16x32 f16 operand layout (verified m118/m120):
//   A[m = lane&15][k = (lane>>4)*8 + j],  B[n = lane&15][k = (lane>>4)*8 + j]
// so a wave's frag load = 16 rows x 128B contiguous -> perfectly coalesced.
// C/D layout (verified m89/m91): n = lane&15, m = (lane>>4)*4 + reg.
//
// Wave = 32 tok x 32 exp x 1024 k. Block 256thr = 4 waves = (eh x kh) over the
// same 32 tokens; kh halves combine through a tiny epilogue LDS slab.
// Live set ~115 VGPR (acc 16 + A-dbuf 32 + B 16 + frags 16 + addrs/misc):
// fits the 128-VGPR budget BY DESIGN (R1/R3/R4 all died on acc spills).
// W pre-split to fp16 hi/lo once (512KB, L2-resident) by w_split.

typedef _Float16 half8  __attribute__((ext_vector_type(8)));
typedef float    floatx4 __attribute__((ext_vector_type(4)));

#define NTOK 16384
#define DDIM 2048
#define NE   64
#define NSTEP 32   // 1024 k per wave / 32 k per mfma step

// ---- kernel 1: split W fp32 -> fp16 hi + lo (64x2048 = 131072 elems) ----
__global__ __launch_bounds__(256) void w_split(const float* __restrict__ W,
                                               _Float16* __restrict__ whi,
                                               _Float16* __restrict__ wlo) {
    const int g = (blockIdx.x * 256 + threadIdx.x) * 8;
    const float4 v0 = *(const float4*)(W + g);
    const float4 v1 = *(const float4*)(W + g + 4);
    float f[8] = {v0.x, v0.y, v0.z, v0.w, v1.x, v1.y, v1.z, v1.w};
    half8 hi, lo;
#pragma unroll
    for (int j = 0; j < 8; ++j) {
        const _Float16 h = (_Float16)f[j];
        hi[j] = h;
        lo[j] = (_Float16)(f[j] - (float)h);
    }
    *(half8*)(whi + g) = hi;
    *(half8*)(wlo + g) = lo;
}

// ---- kernel 2: GEMM + softmax + top-2 ----
__global__ __launch_bounds__(256) void router_mfma(
    const float* __restrict__ x,
    const _Float16* __restrict__ whi,
    const _Float16* __restrict__ wlo,
    float* __restrict__ out)
{
    __shared__ float ex[2 * 64 * 20];   // kh-exchange [eh][lane][16+4pad]
    __shared__ float lg[32 * 68];       // logits slab [m][64+4pad]

    const int tid = threadIdx.x;
    const int L   = tid & 63;
    const int wv  = __builtin_amdgcn_readfirstlane(tid >> 6);
    const int eh  = wv & 1;            // expert half: n in [32*eh, 32*eh+32)
    const int kh  = wv >> 1;           // K half: k in [1024*kh, ...)
    const int c   = L & 15;            // frag row (m or n)
    const int q   = L >> 4;            // frag quad -> k = q*8 + j
    const int tok0 = blockIdx.x * 32;

    // global frag base pointers (per-lane)
    const float*    ax0 = x   + (size_t)(tok0 + c) * DDIM + kh * 1024 + q * 8;
    const float*    ax1 = ax0 + 16 * DDIM;
    const _Float16* b0h = whi + (size_t)(eh * 32 + c) * DDIM + kh * 1024 + q * 8;
    const _Float16* b1h = b0h + 16 * DDIM;
    const _Float16* b0l = wlo + (size_t)(eh * 32 + c) * DDIM + kh * 1024 + q * 8;
    const _Float16* b1l = b0l + 16 * DDIM;

    // A (x) double-buffered: HBM latency must hide one step ahead
    float4 pa[2][2][2];   // [buf][mt][lo/hi half of 8 floats]
    pa[0][0][0] = *(const float4*)(ax0);
    pa[0][0][1] = *(const float4*)(ax0 + 4);
    pa[0][1][0] = *(const float4*)(ax1);
    pa[0][1][1] = *(const float4*)(ax1 + 4);

    floatx4 acc[2][2];    // [mt][nt]
#pragma unroll
    for (int i = 0; i < 2; ++i)
#pragma unroll
        for (int j = 0; j < 2; ++j) acc[i][j] = (floatx4)0.f;

#pragma unroll 2
    for (int s = 0; s < NSTEP; ++s) {
        const int cur = s & 1, nxt = cur ^ 1;
        const int o = s * 32;

        // B frags for this step (L2-resident W; issued first to cover latency)
        half8 bh0 = *(const half8*)(b0h + o);
        half8 bh1 = *(const half8*)(b1h + o);
        half8 bl0 = *(const half8*)(b0l + o);
        half8 bl1 = *(const half8*)(b1l + o);

        // prefetch A for step s+1 (fire-and-forget into the other buffer)
        if (s + 1 < NSTEP) {
            const int on = o + 32;
            pa[nxt][0][0] = *(const float4*)(ax0 + on);
            pa[nxt][0][1] = *(const float4*)(ax0 + on + 4);
            pa[nxt][1][0] = *(const float4*)(ax1 + on);
            pa[nxt][1][1] = *(const float4*)(ax1 + on + 4);
        }

        // convert A(s): fp32 -> hi/lo fp16 frags (~48 VALU, covers B latency)
        half8 ah[2], al[2];
#pragma unroll
        for (int mt = 0; mt < 2; ++mt) {
            const float4 u = pa[cur][mt][0];
            const float4 v = pa[cur][mt][1];
            float f[8] = {u.x, u.y, u.z, u.w, v.x, v.y, v.z, v.w};
#pragma unroll
            for (int j = 0; j < 8; ++j) {
                const _Float16 h = (_Float16)f[j];
                ah[mt][j] = h;
                al[mt][j] = (_Float16)(f[j] - (float)h);
            }
        }

        // 3-pass split MFMA: hh + lh + hl
#pragma unroll
        for (int mt = 0; mt < 2; ++mt) {
            acc[mt][0] = __builtin_amdgcn_mfma_f32_16x16x32_f16(ah[mt], bh0, acc[mt][0], 0, 0, 0);
            acc[mt][0] = __builtin_amdgcn_mfma_f32_16x16x32_f16(al[mt], bh0, acc[mt][0], 0, 0, 0);
            acc[mt][0] = __builtin_amdgcn_mfma_f32_16x16x32_f16(ah[mt], bl0, acc[mt][0], 0, 0, 0);
            acc[mt][1] = __builtin_amdgcn_mfma_f32_16x16x32_f16(ah[mt], bh1, acc[mt][1], 0, 0, 0);
            acc[mt][1] = __builtin_amdgcn_mfma_f32_16x16x32_f16(al[mt], bh1, acc[mt][1], 0, 0, 0);
            acc[mt][1] = __builtin_amdgcn_mfma_f32_16x16x32_f16(ah[mt], bl1, acc[mt][1], 0, 0, 0);
        }
    }

    // ---- combine K halves through LDS ----
    if (kh == 1) {
        float* p = &ex[(eh * 64 + L) * 20];
        *(float4*)(p + 0)  = make_float4(acc[0][0][0], acc[0][0][1], acc[0][0][2], acc[0][0][3]);
        *(float4*)(p + 4)  = make_float4(acc[0][1][0], acc[0][1][1], acc[0][1][2], acc[0][1][3]);
        *(float4*)(p + 8)  = make_float4(acc[1][0][0], acc[1][0][1], acc[1][0][2], acc[1][0][3]);
        *(float4*)(p + 12) = make_float4(acc[1][1][0], acc[1][1][1], acc[1][1][2], acc[1][1][3]);
    }
    __syncthreads();
    if (kh == 0) {
        const float* p = &ex[(eh * 64 + L) * 20];
        float4 t;
        t = *(const float4*)(p + 0);  acc[0][0][0] += t.x; acc[0][0][1] += t.y; acc[0][0][2] += t.z; acc[0][0][3] += t.w;
        t = *(const float4*)(p + 4);  acc[0][1][0] += t.x; acc[0][1][1] += t.y; acc[0][1][2] += t.z; acc[0][1][3] += t.w;
        t = *(const float4*)(p + 8);  acc[1][0][0] += t.x; acc[1][0][1] += t.y; acc[1][0][2] += t.z; acc[1][0][3] += t.w;
        t = *(const float4*)(p + 12); acc[1][1][0] += t.x; acc[1][1][1] += t.y; acc[1][1][2] += t.z; acc[1][1][3] += t.w;
        // scatter to logits slab: C/D layout n=lane&15, m=(lane>>4)*4+reg
#pragma unroll
        for (int mt = 0; mt < 2; ++mt)
#pragma unroll
            for (int nt = 0; nt < 2; ++nt)
#pragma unroll
                for (int r = 0; r < 4; ++r)
                    lg[(mt * 16 + q * 4 + r) * 68 + eh * 32 + nt * 16 + c] = acc[mt][nt][r];
    }
    __syncthreads();

    // ---- softmax + top-2: thread t < 32 owns token tok0+t ----
    if (tid < 32) {
        const int token = tok0 + tid;
        float* row = &lg[tid * 68];
        float p[NE];
#pragma unroll
        for (int e = 0; e < NE; ++e) p[e] = row[e];

        float m = p[0];
#pragma unroll
        for (int e = 1; e < NE; ++e) m = fmaxf(m, p[e]);
        float s = 0.f;
#pragma unroll
        for (int e = 0; e < NE; ++e) { p[e] = expf(p[e] - m); s += p[e]; }
        const float inv = 1.f / s;

        // lax.top_k tie-break = lowest index first -> strict '>' ascending scan
        float v1 = -1.f; int i1 = 0;
#pragma unroll
        for (int e = 0; e < NE; ++e) { if (p[e] > v1) { v1 = p[e]; i1 = e; } }
        float v2 = -1.f; int i2 = 0;
#pragma unroll
        for (int e = 0; e < NE; ++e) { if (e != i1 && p[e] > v2) { v2 = p[e]; i2 = e; } }

        const float ts = v1 + v2;
        float* out_tp = out;              // top_k_probs  [NTOK][2]
        float* out_ti = out + 2 * NTOK;   // top_k_indices[NTOK][2] (float values)
        *(float2*)(out_tp + token * 2) = make_float2(v1 / ts, v2 / ts);
        *(float2*)(out_ti + token * 2) = make_float2((float)i1, (float)i2);

        // renormalized probs back into the slab for a coalesced block write
#pragma unroll
        for (int e = 0; e < NE; ++e) row[e] = p[e] * inv;
    }
    __syncthreads();

    // ---- cooperative coalesced probs write: 32 tok x 64 = 2048 floats ----
    {
        float* out_p = out + 4 * NTOK + (size_t)tok0 * NE;
#pragma unroll
        for (int i = 0; i < 2; ++i) {
            const int f  = tid + 256 * i;       // float4 index, 512 total
            const int r  = f >> 4, c4 = f & 15;
            const float4 v = *(const float4*)&lg[r * 68 + 4 * c4];
            *(float4*)(out_p + f * 4) = v;
        }
    }
}

extern "C" void kernel_launch(void* const* d_in, const int* in_sizes, int n_in,
                              void* d_out, int out_size, void* d_ws, size_t ws_size,
                              hipStream_t stream) {
    const float* x = (const float*)d_in[0];
    const float* W = (const float*)d_in[1];
    float* out     = (float*)d_out;
    _Float16* whi  = (_Float16*)d_ws;          // 256 KB
    _Float16* wlo  = whi + (size_t)NE * DDIM;  // 256 KB (ws >= 512 KB)

    w_split<<<dim3(64), dim3(256), 0, stream>>>(W, whi, wlo);
    router_mfma<<<dim3(NTOK / 32), dim3(256), 0, stream>>>(x, whi, wlo, out);
}